// Round 17
// baseline (7865.858 us; speedup 1.0000x reference)
//
#include <hip/hip_runtime.h>
#include <hip/hip_bf16.h>
#include <cstdint>
#include <cstddef>

#define B_ 64
#define T_ 1024

typedef _Float16 half_t;
typedef __attribute__((ext_vector_type(8))) _Float16 half8;
typedef __attribute__((ext_vector_type(4))) float f32x4;
typedef __attribute__((ext_vector_type(8))) unsigned short ushort8;
typedef unsigned long long ull;

__device__ __forceinline__ float sigm(float x) { return 1.f / (1.f + __expf(-x)); }
__device__ __forceinline__ float tanh_fast(float x) {
  float e = __expf(2.f * x);
  return 1.f - 2.f / (e + 1.f);
}

// Permute columns into gate-interleaved order: dst[k][hc*4+g] = src[k][g*256+hc]
__global__ __launch_bounds__(256) void permute_cols(const float* __restrict__ src,
                                                    float* __restrict__ dst, int K) {
  int idx = blockIdx.x * 256 + threadIdx.x;
  if (idx >= K * 1024) return;
  int n = idx & 1023;
  size_t k = (size_t)(idx >> 10);
  dst[idx] = src[(k << 10) + ((size_t)(n & 3) << 8) + (n >> 2)];
}

// U [256][1024] (gate-blocked) -> MFMA B-fragment order, f16:
// dst flat [wgc(8)][w(4)][n(2)][s(8)][lane(64)][8]
// value = U[k = s*32 + (lane>>4)*8 + j][col' = wgc*128 + w*32 + n*16 + (lane&15)]
__global__ __launch_bounds__(256) void pack_u_mfma(const float* __restrict__ src,
                                                   half_t* __restrict__ dst) {
  int tid = blockIdx.x * 256 + threadIdx.x;  // 32768 lines
  int l = tid & 63;
  int s = (tid >> 6) & 7;
  int n = (tid >> 9) & 1;
  int w = (tid >> 10) & 3;
  int wgc = (tid >> 12) & 7;
  int col = wgc * 128 + w * 32 + n * 16 + (l & 15);
  int hc = col >> 2, g = col & 3;
  int k0 = s * 32 + (l >> 4) * 8;
  half8 v;
#pragma unroll
  for (int j = 0; j < 8; ++j)
    v[j] = (half_t)src[(size_t)(k0 + j) * 1024 + (g << 8) + hc];
  *(half8*)(dst + (size_t)tid * 8) = v;
}

// W0 [64][1024] (gate-blocked) -> MFMA B-frags, f16:
// line = wgc*1024 + w*256 + n*128 + ks*64 + l ;
// value = W0[ks*32+(l>>4)*8+j][col' = wgc*128+w*32+n*16+(l&15)]
__global__ __launch_bounds__(256) void pack_w0_mfma(const float* __restrict__ src,
                                                    half_t* __restrict__ dst) {
  int line = blockIdx.x * 256 + threadIdx.x;  // 8192 lines
  int l = line & 63;
  int ks = (line >> 6) & 1;
  int n = (line >> 7) & 1;
  int w = (line >> 8) & 3;
  int wgc = (line >> 10) & 7;
  int col = wgc * 128 + w * 32 + n * 16 + (l & 15);
  int sc = ((col & 3) << 8) + (col >> 2);
  int k0 = ks * 32 + (l >> 4) * 8;
  half8 v;
#pragma unroll
  for (int j = 0; j < 8; ++j)
    v[j] = (half_t)src[(size_t)(k0 + j) * 1024 + sc];
  *(half8*)(dst + (size_t)line * 8) = v;
}

// W1 [512][1024] (gate-blocked) -> MFMA B-fragment order, f16:
// line idx = (nb*16 + ks)*64 + l ; value = W[ks*32+(l>>4)*8+j][col' = nb*16+(l&15)]
__global__ __launch_bounds__(256) void pack_w1_mfma(const float* __restrict__ src,
                                                    half_t* __restrict__ dst) {
  int tid = blockIdx.x * 256 + threadIdx.x;  // 65536 lines
  int l = tid & 63;
  int ks = (tid >> 6) & 15;
  int nb = tid >> 10;  // 0..63
  int colp = nb * 16 + (l & 15);
  int sc = ((colp & 3) << 8) + (colp >> 2);
  int k0 = ks * 32 + (l >> 4) * 8;
  half8 v;
#pragma unroll
  for (int j = 0; j < 8; ++j)
    v[j] = (half_t)src[(size_t)(k0 + j) * 1024 + sc];
  *(half8*)(dst + (size_t)tid * 8) = v;
}

// x [B][T][64] f32 -> f16 A-layout image xi[bg(4)][t][128 lines][8]:
// line (within bg,t) = ks*64 + q*16 + b ; value = x[bg*16+b][t][ks*32+q*8+j]
__global__ __launch_bounds__(256) void pack_x_f16(const float* __restrict__ x,
                                                  unsigned short* __restrict__ xi) {
  int idx = blockIdx.x * 256 + threadIdx.x;  // 524288 lines
  int b = idx & 15;
  int q = (idx >> 4) & 3;
  int ks = (idx >> 6) & 1;
  int t = (idx >> 7) & 1023;
  int bg = idx >> 17;
  const float* src = x + ((size_t)(bg * 16 + b) * T_ + t) * 64 + ks * 32 + q * 8;
  ushort8 v;
#pragma unroll
  for (int j = 0; j < 8; ++j) {
    half_t h = (half_t)src[j];
    v[j] = __builtin_bit_cast(unsigned short, h);
  }
  *(ushort8*)(xi + (size_t)idx * 8) = v;
}

__global__ __launch_bounds__(256) void init_out(float* __restrict__ out,
                                                const float* __restrict__ bd, int n) {
  int i = blockIdx.x * 256 + threadIdx.x;
  if (i < n) out[i] = bd[0];
}

__global__ __launch_bounds__(256) void diag_out(float* __restrict__ out, int n, float v) {
  int i = blockIdx.x * 256 + threadIdx.x;
  if (i < n) out[i] = (i == 0) ? v : 0.f;
}

// Layer-1 projection (f16 MFMA; K=512), streaming traffic non-temporal.
__global__ __launch_bounds__(256) void proj1_mfma(
    const unsigned short* __restrict__ h0,
    const half_t* __restrict__ Wf, const half_t* __restrict__ Wb,
    const float* __restrict__ bpf, const float* __restrict__ bpb,
    float* __restrict__ xp, int s0, int Tc) {
  const int dir = blockIdx.z;
  const half_t* Wpk = dir ? Wb : Wf;
  const float* bs = dir ? bpb : bpf;
  const int b = blockIdx.y;
  const int mt = blockIdx.x;
  const int tid = threadIdx.x;
  const int l = tid & 63, w = tid >> 6;

  __shared__ __align__(16) unsigned short A_lds[16][520];  // +8 pad

  {
    int r = tid >> 4, c16 = tid & 15;
    int sl = mt * 16 + r;
    int t = dir ? (T_ - 1 - s0 - sl) : (s0 + sl);
    const ushort8* srcp =
        (const ushort8*)(h0 + ((size_t)b * T_ + t) * 512 + c16 * 32);
#pragma unroll
    for (int u = 0; u < 4; ++u)
      *(ushort8*)&A_lds[r][c16 * 32 + u * 8] = __builtin_nontemporal_load(srcp + u);
  }
  __syncthreads();

  f32x4 acc[16];
#pragma unroll
  for (int n = 0; n < 16; ++n) acc[n] = (f32x4){0.f, 0.f, 0.f, 0.f};

  for (int ks = 0; ks < 16; ++ks) {
    half8 a = *(const half8*)&A_lds[l & 15][ks * 32 + (l >> 4) * 8];
    const half_t* bp_ = Wpk + (((size_t)(w * 16) * 16 + ks) * 64 + l) * 8;
#pragma unroll
    for (int n = 0; n < 16; ++n) {
      half8 bfr = *(const half8*)(bp_ + (size_t)n * 16 * 64 * 8);
      acc[n] = __builtin_amdgcn_mfma_f32_16x16x32_f16(a, bfr, acc[n], 0, 0, 0);
    }
  }

#pragma unroll
  for (int n = 0; n < 16; ++n) {
    int col = (w * 16 + n) * 16 + (l & 15);
    float bias = bs[col];
#pragma unroll
    for (int r = 0; r < 4; ++r) {
      int sl = mt * 16 + (l >> 4) * 4 + r;
      __builtin_nontemporal_store(
          acc[n][r] + bias,
          &xp[(((size_t)dir * B_ + b) * Tc + sl) * 1024 + col]);
    }
  }
}

// MFMA scan. Grid 64: unit = blk & 7 (XCD-local), wgc = blk >> 3.
// Exchange (round 17): self-validating tagged u32 words (round-14 mechanism,
// proven correct) + THROTTLED retries (s_sleep backoff between sweeps — the
// round-14 regression was the unthrottled retry storm, same failure mode
// round 9->10 fixed). Chain = publish (fire-and-forget) + consumer bulk load
// that IS the poll: ~1-1.5 LLC round trips vs the flag protocol's ~3.5.
// payl[unit][slot2][4096] u32; word j = (tag16<<16)|f16; tag = tagbase+s+1.
// u32 loads/stores are dword-atomic -> no tag/payload tearing. Own slice is
// taken from LDS (32/256 threads never touch the LLC).
// L0=1: fused input projection, single launch, writes h0 f16 row-major (NT).
// L0=0: xp-mode (layer 1) + fused dense head.
template <int L0>
__global__ __launch_bounds__(256, 1) void lstm_scan_mfma(
    const float* __restrict__ xp,
    const unsigned short* __restrict__ xi,
    const half_t* __restrict__ W0f_, const half_t* __restrict__ W0b_,
    const float* __restrict__ b0f_, const float* __restrict__ b0b_,
    const half_t* __restrict__ Upk_f, const half_t* __restrict__ Upk_b,
    float* __restrict__ carry_c,
    unsigned* __restrict__ payl,
    int s0, int Tc, int tagbase,
    unsigned short* __restrict__ hout,   // f16 row-major [B][T][512]
    const float* __restrict__ Wd, float* __restrict__ out) {
  const int blk = blockIdx.x;
  const int unit = blk & 7;   // XCD-local: same-unit WGs share blk%8
  const int wgc = blk >> 3;
  const int dir = unit & 1;
  const int bg = unit >> 1;
  const int b0u = bg * 16;
  const int tid = threadIdx.x;
  const int l = tid & 63;
  const int w = tid >> 6;

  __shared__ __align__(16) unsigned short A_lds[4096];  // full image (f16)
  __shared__ __align__(16) unsigned short hstage[512];  // this WG's slice
  __shared__ float red_sm[64];

  const half_t* Upk = dir ? Upk_b : Upk_f;
  half8 U[2][8];
  {
    const half_t* up = Upk + (size_t)(wgc * 4 + w) * 8192;
#pragma unroll
    for (int n = 0; n < 2; ++n)
#pragma unroll
      for (int s = 0; s < 8; ++s)
        U[n][s] = *(const half8*)(up + ((size_t)(n * 8 + s) * 64 + l) * 8);
  }

  const int b_lane = 4 * (l >> 4) + (l & 3);
  const int hcb = wgc * 32 + w * 8 + ((l >> 2) & 3);  // + n*4
  const int colb = wgc * 128 + w * 32 + (l & 15);     // + n*16
  float cst[2];
#pragma unroll
  for (int n = 0; n < 2; ++n)
    cst[n] = (s0 == 0) ? 0.f
        : carry_c[((size_t)dir * B_ + b0u + b_lane) * 256 + hcb + n * 4];

  float wdl[2] = {0.f, 0.f};
  half8 W0r[2][2];
  float bias0[2] = {0.f, 0.f};
  const unsigned short* xib = nullptr;
  if (L0) {
    const half_t* W0pk = dir ? W0b_ : W0f_;
    const float* bs0 = dir ? b0b_ : b0f_;
#pragma unroll
    for (int n = 0; n < 2; ++n) {
      bias0[n] = bs0[colb + n * 16];
#pragma unroll
      for (int ks = 0; ks < 2; ++ks)
        W0r[n][ks] = *(const half8*)(W0pk +
            ((size_t)(((wgc * 4 + w) * 2 + n) * 2 + ks) * 64 + l) * 8);
    }
    xib = xi + (size_t)bg * T_ * 1024;
  } else {
    wdl[0] = Wd[dir * 256 + hcb];
    wdl[1] = Wd[dir * 256 + hcb + 4];
  }

  unsigned* payl_u = payl + (size_t)unit * 8192;   // 2 slots x 4096 tagged u32

  if (s0 == 0) {
#pragma unroll
    for (int i = 0; i < 8; ++i) ((unsigned*)A_lds)[tid * 8 + i] = 0u;
  } else {
    // previous launch fully completed (stream order): plain extract, no poll
    unsigned tw[16];
#pragma unroll
    for (int i = 0; i < 16; ++i)
      tw[i] = __hip_atomic_load(payl_u + 4096 + tid * 16 + i,
                                __ATOMIC_RELAXED, __HIP_MEMORY_SCOPE_AGENT);
#pragma unroll
    for (int i = 0; i < 8; ++i)
      ((unsigned*)A_lds)[tid * 8 + i] =
          (tw[2 * i] & 0xFFFFu) | (tw[2 * i + 1] << 16);
  }
  __syncthreads();

  const float* xpu = L0 ? nullptr : (xp + (size_t)(dir * B_ + b0u) * Tc * 1024);

  float xpre[2][4];
  half8 xfre[2];
  {
    if (L0) {
      int t0f = dir ? (T_ - 1 - s0) : s0;
#pragma unroll
      for (int ks = 0; ks < 2; ++ks)
        xfre[ks] = __builtin_nontemporal_load(
            (const half8*)((const half_t*)xib + (size_t)t0f * 1024 +
                           ((ks * 4 + (l >> 4)) * 16 + (l & 15)) * 8));
    } else {
#pragma unroll
      for (int n = 0; n < 2; ++n)
#pragma unroll
        for (int r = 0; r < 4; ++r)
          xpre[n][r] = __builtin_nontemporal_load(
              &xpu[((size_t)(4 * (l >> 4) + r) * Tc) * 1024 + colb + n * 16]);
    }
  }

  const int hbl = (w * 16 + b_lane) * 8 + ((l >> 2) & 3);  // slice-local ushort idx

  for (int sl = 0; sl < Tc; ++sl) {
    const int s = s0 + sl;
    const int t = dir ? (T_ - 1 - s) : s;
    const int slot = s & 1;

    f32x4 acc[2];
    if (L0) {
#pragma unroll
      for (int n = 0; n < 2; ++n)
#pragma unroll
        for (int r = 0; r < 4; ++r) acc[n][r] = bias0[n];
      half8 xa0 = xfre[0], xa1 = xfre[1];
#pragma unroll
      for (int n = 0; n < 2; ++n) {
        acc[n] = __builtin_amdgcn_mfma_f32_16x16x32_f16(xa0, W0r[n][0], acc[n], 0, 0, 0);
        acc[n] = __builtin_amdgcn_mfma_f32_16x16x32_f16(xa1, W0r[n][1], acc[n], 0, 0, 0);
      }
    } else {
#pragma unroll
      for (int n = 0; n < 2; ++n)
#pragma unroll
        for (int r = 0; r < 4; ++r) acc[n][r] = xpre[n][r];
    }

    // A fragments: lane l = h[b = l&15][k = sK*32 + (l>>4)*8 + j]
    half8 a[8];
#pragma unroll
    for (int sK = 0; sK < 8; ++sK)
      a[sK] = *(const half8*)&((const half_t*)A_lds)[((sK * 4 + (l >> 4)) * 16 + (l & 15)) * 8];

#pragma unroll
    for (int sK = 0; sK < 8; ++sK) {
      acc[0] = __builtin_amdgcn_mfma_f32_16x16x32_f16(a[sK], U[0][sK], acc[0], 0, 0, 0);
      acc[1] = __builtin_amdgcn_mfma_f32_16x16x32_f16(a[sK], U[1][sK], acc[1], 0, 0, 0);
    }

    float vhead = 0.f;
    unsigned short hu2[2];
#pragma unroll
    for (int n = 0; n < 2; ++n) {
      // 4x4 transpose across lane group (g = l&3) and regs: u[r] = Z[r][g]
      float v0 = acc[n][0], v1 = acc[n][1], v2 = acc[n][2], v3 = acc[n][3];
      float x0 = __shfl_xor(v1, 1), x1 = __shfl_xor(v0, 1);
      float x2 = __shfl_xor(v3, 1), x3 = __shfl_xor(v2, 1);
      float a0 = (l & 1) ? x0 : v0;
      float a1 = (l & 1) ? v1 : x1;
      float a2 = (l & 1) ? x2 : v2;
      float a3 = (l & 1) ? v3 : x3;
      float y0 = __shfl_xor(a2, 2), y1 = __shfl_xor(a3, 2);
      float y2 = __shfl_xor(a0, 2), y3 = __shfl_xor(a1, 2);
      float u0 = (l & 2) ? y0 : a0;
      float u1 = (l & 2) ? y1 : a1;
      float u2 = (l & 2) ? a2 : y2;
      float u3 = (l & 2) ? a3 : y3;

      float iG = sigm(u0), fG = sigm(u1), gG = tanh_fast(u2), oG = sigm(u3);
      float cn = fG * cst[n] + iG * gG;
      cst[n] = cn;
      float h = oG * tanh_fast(cn);

      if (!L0) vhead += h * wdl[n];
      hu2[n] = __builtin_bit_cast(unsigned short, (half_t)h);
      if (sl == Tc - 1)
        carry_c[((size_t)dir * B_ + b0u + b_lane) * 256 + hcb + n * 4] = cn;
    }
    hstage[hbl] = hu2[0];
    hstage[hbl + 4] = hu2[1];
    if (!L0) {
      vhead += __shfl_xor(vhead, 4);
      vhead += __shfl_xor(vhead, 8);
      if ((l & 12) == 0) red_sm[w * 16 + b_lane] = vhead;
    }
    __syncthreads();  // hstage + red_sm ready; also orders A_lds reads < writes

    const unsigned* hs32 = (const unsigned*)hstage;
    const unsigned want = (unsigned)(tagbase + s + 1);
    // publish: 2 tagged u32 per thread as one u64 (tear-safe: dwords self-tag)
    {
      unsigned h2 = hs32[tid];
      unsigned w0 = (want << 16) | (h2 & 0xFFFFu);
      unsigned w1 = (want << 16) | (h2 >> 16);
      ull pub = ((ull)w1 << 32) | (ull)w0;
      __hip_atomic_store(
          (ull*)(payl_u + (size_t)slot * 4096 + wgc * 512 + tid * 2),
          pub, __ATOMIC_RELAXED, __HIP_MEMORY_SCOPE_AGENT);
    }

    // h0 image write (NT) / fused head add: off the exchange critical path
    if (L0) {
      int bb = tid >> 4, cc = tid & 15;
      __builtin_nontemporal_store(
          hs32[(cc >> 2) * 64 + bb * 4 + (cc & 3)],
          (unsigned*)hout + ((size_t)(b0u + bb) * T_ + t) * 256 + dir * 128 +
              wgc * 16 + cc);
    } else if (tid < 16) {
      atomicAdd(out + (((size_t)(b0u + tid)) << 10) + t,
                (red_sm[tid] + red_sm[16 + tid]) +
                (red_sm[32 + tid] + red_sm[48 + tid]));
    }

    if (sl + 1 < Tc) {
      // next-step input prefetch (NT): hides under the exchange detect latency
      if (L0) {
        int tn = dir ? (T_ - 2 - s) : (s + 1);
#pragma unroll
        for (int ks = 0; ks < 2; ++ks)
          xfre[ks] = __builtin_nontemporal_load(
              (const half8*)((const half_t*)xib + (size_t)tn * 1024 +
                             ((ks * 4 + (l >> 4)) * 16 + (l & 15)) * 8));
      } else {
#pragma unroll
        for (int n = 0; n < 2; ++n)
#pragma unroll
          for (int r = 0; r < 4; ++r)
            xpre[n][r] = __builtin_nontemporal_load(
                &xpu[((size_t)(4 * (l >> 4) + r) * Tc + sl + 1) * 1024 + colb + n * 16]);
      }

      // consume: bulk load IS the poll; THROTTLED retries (s_sleep backoff)
      unsigned dd[8];
      const int g = tid >> 5;  // producer WG of this thread's 16 tagged words
      if (g == wgc) {
#pragma unroll
        for (int i = 0; i < 8; ++i) dd[i] = hs32[(tid & 31) * 8 + i];
      } else {
        const unsigned* src = payl_u + (size_t)slot * 4096 + tid * 16;
        unsigned tw[16];
#pragma unroll
        for (int i = 0; i < 16; ++i)
          tw[i] = __hip_atomic_load(src + i, __ATOMIC_RELAXED,
                                    __HIP_MEMORY_SCOPE_AGENT);
        for (;;) {
          bool bad = false;
#pragma unroll
          for (int i = 0; i < 16; ++i)
            if ((tw[i] >> 16) != want) bad = true;
          if (!bad) break;
          __builtin_amdgcn_s_sleep(1);
#pragma unroll
          for (int i = 0; i < 16; ++i)
            if ((tw[i] >> 16) != want)
              tw[i] = __hip_atomic_load(src + i, __ATOMIC_RELAXED,
                                        __HIP_MEMORY_SCOPE_AGENT);
        }
#pragma unroll
        for (int i = 0; i < 8; ++i)
          dd[i] = (tw[2 * i] & 0xFFFFu) | (tw[2 * i + 1] << 16);
      }
#pragma unroll
      for (int i = 0; i < 8; ++i)
        ((unsigned*)A_lds)[tid * 8 + i] = dd[i];
      __syncthreads();
    }
  }
}

extern "C" void kernel_launch(void* const* d_in, const int* in_sizes, int n_in,
                              void* d_out, int out_size, void* d_ws, size_t ws_size,
                              hipStream_t stream) {
  const float* x   = (const float*)d_in[0];
  const float* W0f = (const float*)d_in[1];
  const float* U0f = (const float*)d_in[2];
  const float* b0f = (const float*)d_in[3];
  const float* W0b = (const float*)d_in[4];
  const float* U0b = (const float*)d_in[5];
  const float* b0b = (const float*)d_in[6];
  const float* W1f = (const float*)d_in[7];
  const float* U1f = (const float*)d_in[8];
  const float* b1f = (const float*)d_in[9];
  const float* W1b = (const float*)d_in[10];
  const float* U1b = (const float*)d_in[11];
  const float* b1b = (const float*)d_in[12];
  const float* Wd  = (const float*)d_in[13];
  const float* bd  = (const float*)d_in[14];
  float* out = (float*)d_out;
  char* ws = (char*)d_ws;

  const size_t H0_BYTES   = (size_t)B_ * T_ * 512 * 2;     // 64 MiB f16
  const size_t UPK_BYTES  = (size_t)262144 * 2;            // 512 KiB
  const size_t W0PK_BYTES = (size_t)8192 * 8 * 2;          // 128 KiB f16
  const size_t W1PK_BYTES = (size_t)512 * 1024 * 2;        // 1 MiB f16
  const size_t XI_BYTES   = (size_t)B_ * T_ * 64 * 2;      // 8 MiB f16
  const size_t BP_BYTES   = 1024 * 4;
  const size_t CC_BYTES   = (size_t)2 * B_ * 256 * 4;      // 128 KiB
  const size_t PL_BYTES   = (size_t)8 * 8192 * 4;          // 256 KiB tagged payload
  const size_t REPACK = 4 * UPK_BYTES + 2 * W0PK_BYTES + 2 * W1PK_BYTES +
                        XI_BYTES + 4 * BP_BYTES + CC_BYTES + PL_BYTES + 1024;

  int Tc = 0;
  for (int tc = 256; tc >= 64; tc >>= 1) {
    size_t xpb = (size_t)2 * B_ * tc * 1024 * 4;
    if (H0_BYTES + REPACK + xpb <= ws_size) { Tc = tc; break; }
  }
  if (!Tc) {
    float v = 1000.f + (float)(ws_size >> 20);
    diag_out<<<(out_size + 255) / 256, 256, 0, stream>>>(out, out_size, v);
    return;
  }

  size_t off = 0;
  unsigned short* h0 = (unsigned short*)(ws + off); off += H0_BYTES;
  half_t* Up00 = (half_t*)(ws + off); off += UPK_BYTES;
  half_t* Up01 = (half_t*)(ws + off); off += UPK_BYTES;
  half_t* Up10 = (half_t*)(ws + off); off += UPK_BYTES;
  half_t* Up11 = (half_t*)(ws + off); off += UPK_BYTES;
  half_t* W0pf = (half_t*)(ws + off); off += W0PK_BYTES;
  half_t* W0pb = (half_t*)(ws + off); off += W0PK_BYTES;
  half_t* W1pf = (half_t*)(ws + off); off += W1PK_BYTES;
  half_t* W1pb = (half_t*)(ws + off); off += W1PK_BYTES;
  unsigned short* xi = (unsigned short*)(ws + off); off += XI_BYTES;
  float* bp0f = (float*)(ws + off); off += BP_BYTES;
  float* bp0b = (float*)(ws + off); off += BP_BYTES;
  float* bp1f = (float*)(ws + off); off += BP_BYTES;
  float* bp1b = (float*)(ws + off); off += BP_BYTES;
  float* carry_c = (float*)(ws + off); off += CC_BYTES;
  unsigned* payl = (unsigned*)(ws + off); off += PL_BYTES;
  off = (off + 255) & ~(size_t)255;
  float* xpc = (float*)(ws + off);

  // --- repacking ---
  pack_u_mfma<<<128, 256, 0, stream>>>(U0f, Up00);
  pack_u_mfma<<<128, 256, 0, stream>>>(U0b, Up01);
  pack_u_mfma<<<128, 256, 0, stream>>>(U1f, Up10);
  pack_u_mfma<<<128, 256, 0, stream>>>(U1b, Up11);
  pack_w0_mfma<<<32, 256, 0, stream>>>(W0f, W0pf);
  pack_w0_mfma<<<32, 256, 0, stream>>>(W0b, W0pb);
  pack_w1_mfma<<<256, 256, 0, stream>>>(W1f, W1pf);
  pack_w1_mfma<<<256, 256, 0, stream>>>(W1b, W1pb);
  pack_x_f16<<<2048, 256, 0, stream>>>(x, xi);
  permute_cols<<<4, 256, 0, stream>>>(b0f, bp0f, 1);
  permute_cols<<<4, 256, 0, stream>>>(b0b, bp0b, 1);
  permute_cols<<<4, 256, 0, stream>>>(b1f, bp1f, 1);
  permute_cols<<<4, 256, 0, stream>>>(b1b, bp1b, 1);

  // ---- layer 0: fused proj+scan, single launch; tags 1..1024 ----
  lstm_scan_mfma<1><<<64, 256, 0, stream>>>(
      nullptr, xi, W0pf, W0pb, bp0f, bp0b, Up00, Up01, carry_c,
      payl, 0, T_, 0, h0, nullptr, nullptr);

  // ---- layer 1: h0 -> out (fused dense head); tags 1025..2048 ----
  init_out<<<(out_size + 255) / 256, 256, 0, stream>>>(out, bd, out_size);
  const int nch = T_ / Tc;
  const dim3 pgrid(Tc / 16, B_, 2);
  for (int ci = 0; ci < nch; ++ci) {
    int s0c = ci * Tc;
    proj1_mfma<<<pgrid, 256, 0, stream>>>(h0, W1pf, W1pb, bp1f, bp1b,
                                          xpc, s0c, Tc);
    lstm_scan_mfma<0><<<64, 256, 0, stream>>>(
        xpc, nullptr, nullptr, nullptr, nullptr, nullptr, Up10, Up11, carry_c,
        payl, s0c, Tc, 1024, nullptr, Wd, out);
  }
}

// Round 18
// 6438.260 us; speedup vs baseline: 1.2217x; 1.2217x over previous
//
#include <hip/hip_runtime.h>
#include <hip/hip_bf16.h>
#include <cstdint>
#include <cstddef>

#define B_ 64
#define T_ 1024

typedef _Float16 half_t;
typedef __attribute__((ext_vector_type(8))) _Float16 half8;
typedef __attribute__((ext_vector_type(4))) float f32x4;
typedef __attribute__((ext_vector_type(8))) unsigned short ushort8;

__device__ __forceinline__ float sigm(float x) { return 1.f / (1.f + __expf(-x)); }
__device__ __forceinline__ float tanh_fast(float x) {
  float e = __expf(2.f * x);
  return 1.f - 2.f / (e + 1.f);
}

// Permute columns into gate-interleaved order: dst[k][hc*4+g] = src[k][g*256+hc]
__global__ __launch_bounds__(256) void permute_cols(const float* __restrict__ src,
                                                    float* __restrict__ dst, int K) {
  int idx = blockIdx.x * 256 + threadIdx.x;
  if (idx >= K * 1024) return;
  int n = idx & 1023;
  size_t k = (size_t)(idx >> 10);
  dst[idx] = src[(k << 10) + ((size_t)(n & 3) << 8) + (n >> 2)];
}

// U [256][1024] (gate-blocked) -> MFMA B-fragment order, f16:
// dst flat [wgc(8)][w(4)][n(2)][s(8)][lane(64)][8]
// value = U[k = s*32 + (lane>>4)*8 + j][col' = wgc*128 + w*32 + n*16 + (lane&15)]
__global__ __launch_bounds__(256) void pack_u_mfma(const float* __restrict__ src,
                                                   half_t* __restrict__ dst) {
  int tid = blockIdx.x * 256 + threadIdx.x;  // 32768 lines
  int l = tid & 63;
  int s = (tid >> 6) & 7;
  int n = (tid >> 9) & 1;
  int w = (tid >> 10) & 3;
  int wgc = (tid >> 12) & 7;
  int col = wgc * 128 + w * 32 + n * 16 + (l & 15);
  int hc = col >> 2, g = col & 3;
  int k0 = s * 32 + (l >> 4) * 8;
  half8 v;
#pragma unroll
  for (int j = 0; j < 8; ++j)
    v[j] = (half_t)src[(size_t)(k0 + j) * 1024 + (g << 8) + hc];
  *(half8*)(dst + (size_t)tid * 8) = v;
}

// W0 [64][1024] (gate-blocked) -> MFMA B-frags, f16:
// line = wgc*1024 + w*256 + n*128 + ks*64 + l ;
// value = W0[ks*32+(l>>4)*8+j][col' = wgc*128+w*32+n*16+(l&15)]
__global__ __launch_bounds__(256) void pack_w0_mfma(const float* __restrict__ src,
                                                    half_t* __restrict__ dst) {
  int line = blockIdx.x * 256 + threadIdx.x;  // 8192 lines
  int l = line & 63;
  int ks = (line >> 6) & 1;
  int n = (line >> 7) & 1;
  int w = (line >> 8) & 3;
  int wgc = (line >> 10) & 7;
  int col = wgc * 128 + w * 32 + n * 16 + (l & 15);
  int sc = ((col & 3) << 8) + (col >> 2);
  int k0 = ks * 32 + (l >> 4) * 8;
  half8 v;
#pragma unroll
  for (int j = 0; j < 8; ++j)
    v[j] = (half_t)src[(size_t)(k0 + j) * 1024 + sc];
  *(half8*)(dst + (size_t)line * 8) = v;
}

// W1 [512][1024] (gate-blocked) -> MFMA B-fragment order, f16:
// line idx = (nb*16 + ks)*64 + l ; value = W[ks*32+(l>>4)*8+j][col' = nb*16+(l&15)]
__global__ __launch_bounds__(256) void pack_w1_mfma(const float* __restrict__ src,
                                                    half_t* __restrict__ dst) {
  int tid = blockIdx.x * 256 + threadIdx.x;  // 65536 lines
  int l = tid & 63;
  int ks = (tid >> 6) & 15;
  int nb = tid >> 10;  // 0..63
  int colp = nb * 16 + (l & 15);
  int sc = ((colp & 3) << 8) + (colp >> 2);
  int k0 = ks * 32 + (l >> 4) * 8;
  half8 v;
#pragma unroll
  for (int j = 0; j < 8; ++j)
    v[j] = (half_t)src[(size_t)(k0 + j) * 1024 + sc];
  *(half8*)(dst + (size_t)tid * 8) = v;
}

// x [B][T][64] f32 -> f16 A-layout image xi[bg(4)][t][128 lines][8]:
// line (within bg,t) = ks*64 + q*16 + b ; value = x[bg*16+b][t][ks*32+q*8+j]
__global__ __launch_bounds__(256) void pack_x_f16(const float* __restrict__ x,
                                                  unsigned short* __restrict__ xi) {
  int idx = blockIdx.x * 256 + threadIdx.x;  // 524288 lines
  int b = idx & 15;
  int q = (idx >> 4) & 3;
  int ks = (idx >> 6) & 1;
  int t = (idx >> 7) & 1023;
  int bg = idx >> 17;
  const float* src = x + ((size_t)(bg * 16 + b) * T_ + t) * 64 + ks * 32 + q * 8;
  ushort8 v;
#pragma unroll
  for (int j = 0; j < 8; ++j) {
    half_t h = (half_t)src[j];
    v[j] = __builtin_bit_cast(unsigned short, h);
  }
  *(ushort8*)(xi + (size_t)idx * 8) = v;
}

__global__ __launch_bounds__(256) void init_out(float* __restrict__ out,
                                                const float* __restrict__ bd, int n) {
  int i = blockIdx.x * 256 + threadIdx.x;
  if (i < n) out[i] = bd[0];
}

__global__ __launch_bounds__(256) void diag_out(float* __restrict__ out, int n, float v) {
  int i = blockIdx.x * 256 + threadIdx.x;
  if (i < n) out[i] = (i == 0) ? v : 0.f;
}

// Layer-1 projection (f16 MFMA; K=512), streaming traffic non-temporal.
__global__ __launch_bounds__(256) void proj1_mfma(
    const unsigned short* __restrict__ h0,
    const half_t* __restrict__ Wf, const half_t* __restrict__ Wb,
    const float* __restrict__ bpf, const float* __restrict__ bpb,
    float* __restrict__ xp, int s0, int Tc) {
  const int dir = blockIdx.z;
  const half_t* Wpk = dir ? Wb : Wf;
  const float* bs = dir ? bpb : bpf;
  const int b = blockIdx.y;
  const int mt = blockIdx.x;
  const int tid = threadIdx.x;
  const int l = tid & 63, w = tid >> 6;

  __shared__ __align__(16) unsigned short A_lds[16][520];  // +8 pad

  {
    int r = tid >> 4, c16 = tid & 15;
    int sl = mt * 16 + r;
    int t = dir ? (T_ - 1 - s0 - sl) : (s0 + sl);
    const ushort8* srcp =
        (const ushort8*)(h0 + ((size_t)b * T_ + t) * 512 + c16 * 32);
#pragma unroll
    for (int u = 0; u < 4; ++u)
      *(ushort8*)&A_lds[r][c16 * 32 + u * 8] = __builtin_nontemporal_load(srcp + u);
  }
  __syncthreads();

  f32x4 acc[16];
#pragma unroll
  for (int n = 0; n < 16; ++n) acc[n] = (f32x4){0.f, 0.f, 0.f, 0.f};

  for (int ks = 0; ks < 16; ++ks) {
    half8 a = *(const half8*)&A_lds[l & 15][ks * 32 + (l >> 4) * 8];
    const half_t* bp_ = Wpk + (((size_t)(w * 16) * 16 + ks) * 64 + l) * 8;
#pragma unroll
    for (int n = 0; n < 16; ++n) {
      half8 bfr = *(const half8*)(bp_ + (size_t)n * 16 * 64 * 8);
      acc[n] = __builtin_amdgcn_mfma_f32_16x16x32_f16(a, bfr, acc[n], 0, 0, 0);
    }
  }

#pragma unroll
  for (int n = 0; n < 16; ++n) {
    int col = (w * 16 + n) * 16 + (l & 15);
    float bias = bs[col];
#pragma unroll
    for (int r = 0; r < 4; ++r) {
      int sl = mt * 16 + (l >> 4) * 4 + r;
      __builtin_nontemporal_store(
          acc[n][r] + bias,
          &xp[(((size_t)dir * B_ + b) * Tc + sl) * 1024 + col]);
    }
  }
}

// MFMA scan. Grid 32 x 512 threads: unit = blk & 7 (XCD-local), wgc = blk>>3
// in [0,4). Each WG = 8 waves = 2 merged round-16 producer slots
// (wgco = wgc*2 + (w8>>2), w = w8&3) -> per-wave work identical to round 16
// (32 gate-cols, 2 accs, 16 MFMAs), but producers/step per unit: 8 -> 4
// (halves straggler spread + flag-poll fan-in; 2 of 8 slices come from LDS).
// Protocol = round 16 (best, 6.58 ms): payload publish -> vmcnt(0) drain ->
// tagged flag -> throttled poll (tid<4, own skipped) -> bulk load.
// Streaming traffic (h0 stores, xi/xp loads) non-temporal.
// L0=1: fused input projection, single launch over T, writes h0 f16 row-major.
// L0=0: xp-mode (layer 1) + fused dense head.
template <int L0>
__global__ __launch_bounds__(512, 1) void lstm_scan_mfma(
    const float* __restrict__ xp,
    const unsigned short* __restrict__ xi,
    const half_t* __restrict__ W0f_, const half_t* __restrict__ W0b_,
    const float* __restrict__ b0f_, const float* __restrict__ b0b_,
    const half_t* __restrict__ Upk_f, const half_t* __restrict__ Upk_b,
    float* __restrict__ carry_c,
    unsigned* __restrict__ payl, unsigned* __restrict__ flagw,
    int s0, int Tc, int tagbase,
    unsigned short* __restrict__ hout,   // f16 row-major [B][T][512]
    const float* __restrict__ Wd, float* __restrict__ out) {
  const int blk = blockIdx.x;
  const int unit = blk & 7;   // XCD-local: same-unit WGs share blk%8
  const int wgc = blk >> 3;   // 0..3
  const int dir = unit & 1;
  const int bg = unit >> 1;
  const int b0u = bg * 16;
  const int tid = threadIdx.x;   // 0..511
  const int l = tid & 63;
  const int w8 = tid >> 6;       // 0..7
  const int wgco = wgc * 2 + (w8 >> 2);  // round-16 producer slot (0..7)
  const int w = w8 & 3;                  // round-16 wave-in-slot

  __shared__ __align__(16) unsigned short A_lds[4096];   // full image (f16)
  __shared__ __align__(16) unsigned short hstage[1024];  // WG's 2 slices
  __shared__ float red_sm[128];

  const half_t* Upk = dir ? Upk_b : Upk_f;
  half8 U[2][8];
  {
    const half_t* up = Upk + (size_t)(wgco * 4 + w) * 8192;
#pragma unroll
    for (int n = 0; n < 2; ++n)
#pragma unroll
      for (int s = 0; s < 8; ++s)
        U[n][s] = *(const half8*)(up + ((size_t)(n * 8 + s) * 64 + l) * 8);
  }

  const int b_lane = 4 * (l >> 4) + (l & 3);
  const int hcb = wgco * 32 + w * 8 + ((l >> 2) & 3);  // + n*4
  const int colb = wgco * 128 + w * 32 + (l & 15);     // + n*16
  float cst[2];
#pragma unroll
  for (int n = 0; n < 2; ++n)
    cst[n] = (s0 == 0) ? 0.f
        : carry_c[((size_t)dir * B_ + b0u + b_lane) * 256 + hcb + n * 4];

  float wdl[2] = {0.f, 0.f};
  half8 W0r[2][2];
  float bias0[2] = {0.f, 0.f};
  const unsigned short* xib = nullptr;
  if (L0) {
    const half_t* W0pk = dir ? W0b_ : W0f_;
    const float* bs0 = dir ? b0b_ : b0f_;
#pragma unroll
    for (int n = 0; n < 2; ++n) {
      bias0[n] = bs0[colb + n * 16];
#pragma unroll
      for (int ks = 0; ks < 2; ++ks)
        W0r[n][ks] = *(const half8*)(W0pk +
            ((size_t)(((wgco * 4 + w) * 2 + n) * 2 + ks) * 64 + l) * 8);
    }
    xib = xi + (size_t)bg * T_ * 1024;
  } else {
    wdl[0] = Wd[dir * 256 + hcb];
    wdl[1] = Wd[dir * 256 + hcb + 4];
  }

  unsigned* payl_u = payl + (size_t)unit * 4096;   // 2 slots x 2048 u32
  unsigned* flag_u = flagw + unit * 16;            // 2 slots x 8 (4 used)

  if (s0 == 0) {
#pragma unroll
    for (int i = 0; i < 4; ++i) ((unsigned*)A_lds)[tid * 4 + i] = 0u;
  } else {
    unsigned dd[4];
#pragma unroll
    for (int i = 0; i < 4; ++i)
      dd[i] = __hip_atomic_load(payl_u + 2048 + tid * 4 + i,
                                __ATOMIC_RELAXED, __HIP_MEMORY_SCOPE_AGENT);
#pragma unroll
    for (int i = 0; i < 4; ++i)
      ((unsigned*)A_lds)[tid * 4 + i] = dd[i];
  }
  __syncthreads();

  const float* xpu = L0 ? nullptr : (xp + (size_t)(dir * B_ + b0u) * Tc * 1024);

  float xpre[2][4];
  half8 xfre[2];
  {
    if (L0) {
      int t0f = dir ? (T_ - 1 - s0) : s0;
#pragma unroll
      for (int ks = 0; ks < 2; ++ks)
        xfre[ks] = __builtin_nontemporal_load(
            (const half8*)((const half_t*)xib + (size_t)t0f * 1024 +
                           ((ks * 4 + (l >> 4)) * 16 + (l & 15)) * 8));
    } else {
#pragma unroll
      for (int n = 0; n < 2; ++n)
#pragma unroll
        for (int r = 0; r < 4; ++r)
          xpre[n][r] = __builtin_nontemporal_load(
              &xpu[((size_t)(4 * (l >> 4) + r) * Tc) * 1024 + colb + n * 16]);
    }
  }

  // hstage u16 index: slice (w8>>2) then round-16 slice-local layout
  const int hbl = (w8 >> 2) * 512 + (w * 16 + b_lane) * 8 + ((l >> 2) & 3);

  for (int sl = 0; sl < Tc; ++sl) {
    const int s = s0 + sl;
    const int t = dir ? (T_ - 1 - s) : s;
    const int slot = s & 1;

    f32x4 acc[2];
    if (L0) {
#pragma unroll
      for (int n = 0; n < 2; ++n)
#pragma unroll
        for (int r = 0; r < 4; ++r) acc[n][r] = bias0[n];
      half8 xa0 = xfre[0], xa1 = xfre[1];
#pragma unroll
      for (int n = 0; n < 2; ++n) {
        acc[n] = __builtin_amdgcn_mfma_f32_16x16x32_f16(xa0, W0r[n][0], acc[n], 0, 0, 0);
        acc[n] = __builtin_amdgcn_mfma_f32_16x16x32_f16(xa1, W0r[n][1], acc[n], 0, 0, 0);
      }
    } else {
#pragma unroll
      for (int n = 0; n < 2; ++n)
#pragma unroll
        for (int r = 0; r < 4; ++r) acc[n][r] = xpre[n][r];
    }

    // A fragments: lane l = h[b = l&15][k = sK*32 + (l>>4)*8 + j]
    half8 a[8];
#pragma unroll
    for (int sK = 0; sK < 8; ++sK)
      a[sK] = *(const half8*)&((const half_t*)A_lds)[((sK * 4 + (l >> 4)) * 16 + (l & 15)) * 8];

#pragma unroll
    for (int sK = 0; sK < 8; ++sK) {
      acc[0] = __builtin_amdgcn_mfma_f32_16x16x32_f16(a[sK], U[0][sK], acc[0], 0, 0, 0);
      acc[1] = __builtin_amdgcn_mfma_f32_16x16x32_f16(a[sK], U[1][sK], acc[1], 0, 0, 0);
    }

    float vhead = 0.f;
    unsigned short hu2[2];
#pragma unroll
    for (int n = 0; n < 2; ++n) {
      // 4x4 transpose across lane group (g = l&3) and regs: u[r] = Z[r][g]
      float v0 = acc[n][0], v1 = acc[n][1], v2 = acc[n][2], v3 = acc[n][3];
      float x0 = __shfl_xor(v1, 1), x1 = __shfl_xor(v0, 1);
      float x2 = __shfl_xor(v3, 1), x3 = __shfl_xor(v2, 1);
      float a0 = (l & 1) ? x0 : v0;
      float a1 = (l & 1) ? v1 : x1;
      float a2 = (l & 1) ? x2 : v2;
      float a3 = (l & 1) ? v3 : x3;
      float y0 = __shfl_xor(a2, 2), y1 = __shfl_xor(a3, 2);
      float y2 = __shfl_xor(a0, 2), y3 = __shfl_xor(a1, 2);
      float u0 = (l & 2) ? y0 : a0;
      float u1 = (l & 2) ? y1 : a1;
      float u2 = (l & 2) ? a2 : y2;
      float u3 = (l & 2) ? a3 : y3;

      float iG = sigm(u0), fG = sigm(u1), gG = tanh_fast(u2), oG = sigm(u3);
      float cn = fG * cst[n] + iG * gG;
      cst[n] = cn;
      float h = oG * tanh_fast(cn);

      if (!L0) vhead += h * wdl[n];
      hu2[n] = __builtin_bit_cast(unsigned short, (half_t)h);
      if (sl == Tc - 1)
        carry_c[((size_t)dir * B_ + b0u + b_lane) * 256 + hcb + n * 4] = cn;
    }
    hstage[hbl] = hu2[0];
    hstage[hbl + 4] = hu2[1];
    if (!L0) {
      vhead += __shfl_xor(vhead, 4);
      vhead += __shfl_xor(vhead, 8);
      if ((l & 12) == 0) red_sm[w8 * 16 + b_lane] = vhead;
    }
    __syncthreads();  // hstage + red_sm ready

    const unsigned* hs32 = (const unsigned*)hstage;  // u32[512]
    // coalesced payload publish: one u32 per thread = WG's 2KB (2 slices)
    __hip_atomic_store(payl_u + slot * 2048 + wgc * 512 + tid, hs32[tid],
                       __ATOMIC_RELAXED, __HIP_MEMORY_SCOPE_AGENT);

    // drain the payload store, then publish the flag
    asm volatile("s_waitcnt vmcnt(0)" ::: "memory");
    __syncthreads();
    const unsigned want = (unsigned)(tagbase + s + 1);
    if (tid == 0)
      __hip_atomic_store(flag_u + slot * 8 + wgc, want,
                         __ATOMIC_RELAXED, __HIP_MEMORY_SCOPE_AGENT);

    // h0 image write (NT) / fused head add: outside the drain window
    if (L0) {
      int sub = tid >> 8, r = tid & 255;
      int bb = r >> 4, cc = r & 15;
      __builtin_nontemporal_store(
          hs32[sub * 256 + (cc >> 2) * 64 + bb * 4 + (cc & 3)],
          (unsigned*)hout + ((size_t)(b0u + bb) * T_ + t) * 256 + dir * 128 +
              (wgc * 2 + sub) * 16 + cc);
    } else if (tid < 16) {
      float sum = ((red_sm[tid] + red_sm[16 + tid]) +
                   (red_sm[32 + tid] + red_sm[48 + tid])) +
                  ((red_sm[64 + tid] + red_sm[80 + tid]) +
                   (red_sm[96 + tid] + red_sm[112 + tid]));
      atomicAdd(out + (((size_t)(b0u + tid)) << 10) + t, sum);
    }

    if (sl + 1 < Tc) {
      // next-step input prefetch (NT): hides under the flag poll
      if (L0) {
        int tn = dir ? (T_ - 2 - s) : (s + 1);
#pragma unroll
        for (int ks = 0; ks < 2; ++ks)
          xfre[ks] = __builtin_nontemporal_load(
              (const half8*)((const half_t*)xib + (size_t)tn * 1024 +
                             ((ks * 4 + (l >> 4)) * 16 + (l & 15)) * 8));
      } else {
#pragma unroll
        for (int n = 0; n < 2; ++n)
#pragma unroll
          for (int r = 0; r < 4; ++r)
            xpre[n][r] = __builtin_nontemporal_load(
                &xpu[((size_t)(4 * (l >> 4) + r) * Tc + sl + 1) * 1024 + colb + n * 16]);
      }

      // throttled poll: 4 pollers (own flag skipped), hot spin
      if (tid < 4 && tid != wgc) {
        while (__hip_atomic_load(flag_u + slot * 8 + tid, __ATOMIC_RELAXED,
                                 __HIP_MEMORY_SCOPE_AGENT) != want) {}
      }
      __syncthreads();
      // bulk load: 4 u32/thread; own WG's 2 slices come from LDS
      unsigned dd[4];
      const int g = tid >> 6;  // producer slot (0..7) of words tid*4..tid*4+3
      if ((g >> 1) == wgc) {
#pragma unroll
        for (int i = 0; i < 4; ++i)
          dd[i] = hs32[(g & 1) * 256 + (tid & 63) * 4 + i];
      } else {
#pragma unroll
        for (int i = 0; i < 4; ++i)
          dd[i] = __hip_atomic_load(payl_u + slot * 2048 + tid * 4 + i,
                                    __ATOMIC_RELAXED, __HIP_MEMORY_SCOPE_AGENT);
      }
#pragma unroll
      for (int i = 0; i < 4; ++i)
        ((unsigned*)A_lds)[tid * 4 + i] = dd[i];
      __syncthreads();
    }
  }
}

extern "C" void kernel_launch(void* const* d_in, const int* in_sizes, int n_in,
                              void* d_out, int out_size, void* d_ws, size_t ws_size,
                              hipStream_t stream) {
  const float* x   = (const float*)d_in[0];
  const float* W0f = (const float*)d_in[1];
  const float* U0f = (const float*)d_in[2];
  const float* b0f = (const float*)d_in[3];
  const float* W0b = (const float*)d_in[4];
  const float* U0b = (const float*)d_in[5];
  const float* b0b = (const float*)d_in[6];
  const float* W1f = (const float*)d_in[7];
  const float* U1f = (const float*)d_in[8];
  const float* b1f = (const float*)d_in[9];
  const float* W1b = (const float*)d_in[10];
  const float* U1b = (const float*)d_in[11];
  const float* b1b = (const float*)d_in[12];
  const float* Wd  = (const float*)d_in[13];
  const float* bd  = (const float*)d_in[14];
  float* out = (float*)d_out;
  char* ws = (char*)d_ws;

  const size_t H0_BYTES   = (size_t)B_ * T_ * 512 * 2;     // 64 MiB f16
  const size_t UPK_BYTES  = (size_t)262144 * 2;            // 512 KiB
  const size_t W0PK_BYTES = (size_t)8192 * 8 * 2;          // 128 KiB f16
  const size_t W1PK_BYTES = (size_t)512 * 1024 * 2;        // 1 MiB f16
  const size_t XI_BYTES   = (size_t)B_ * T_ * 64 * 2;      // 8 MiB f16
  const size_t BP_BYTES   = 1024 * 4;
  const size_t CC_BYTES   = (size_t)2 * B_ * 256 * 4;      // 128 KiB
  const size_t PL_BYTES   = (size_t)8 * 4096 * 4;          // 128 KiB payload
  const size_t FL_BYTES   = 1024;
  const size_t REPACK = 4 * UPK_BYTES + 2 * W0PK_BYTES + 2 * W1PK_BYTES +
                        XI_BYTES + 4 * BP_BYTES + CC_BYTES + PL_BYTES +
                        FL_BYTES + 1024;

  int Tc = 0;
  for (int tc = 256; tc >= 64; tc >>= 1) {
    size_t xpb = (size_t)2 * B_ * tc * 1024 * 4;
    if (H0_BYTES + REPACK + xpb <= ws_size) { Tc = tc; break; }
  }
  if (!Tc) {
    float v = 1000.f + (float)(ws_size >> 20);
    diag_out<<<(out_size + 255) / 256, 256, 0, stream>>>(out, out_size, v);
    return;
  }

  size_t off = 0;
  unsigned short* h0 = (unsigned short*)(ws + off); off += H0_BYTES;
  half_t* Up00 = (half_t*)(ws + off); off += UPK_BYTES;
  half_t* Up01 = (half_t*)(ws + off); off += UPK_BYTES;
  half_t* Up10 = (half_t*)(ws + off); off += UPK_BYTES;
  half_t* Up11 = (half_t*)(ws + off); off += UPK_BYTES;
  half_t* W0pf = (half_t*)(ws + off); off += W0PK_BYTES;
  half_t* W0pb = (half_t*)(ws + off); off += W0PK_BYTES;
  half_t* W1pf = (half_t*)(ws + off); off += W1PK_BYTES;
  half_t* W1pb = (half_t*)(ws + off); off += W1PK_BYTES;
  unsigned short* xi = (unsigned short*)(ws + off); off += XI_BYTES;
  float* bp0f = (float*)(ws + off); off += BP_BYTES;
  float* bp0b = (float*)(ws + off); off += BP_BYTES;
  float* bp1f = (float*)(ws + off); off += BP_BYTES;
  float* bp1b = (float*)(ws + off); off += BP_BYTES;
  float* carry_c = (float*)(ws + off); off += CC_BYTES;
  unsigned* payl = (unsigned*)(ws + off); off += PL_BYTES;
  unsigned* flagw = (unsigned*)(ws + off); off += FL_BYTES;
  off = (off + 255) & ~(size_t)255;
  float* xpc = (float*)(ws + off);

  // --- repacking ---
  pack_u_mfma<<<128, 256, 0, stream>>>(U0f, Up00);
  pack_u_mfma<<<128, 256, 0, stream>>>(U0b, Up01);
  pack_u_mfma<<<128, 256, 0, stream>>>(U1f, Up10);
  pack_u_mfma<<<128, 256, 0, stream>>>(U1b, Up11);
  pack_w0_mfma<<<32, 256, 0, stream>>>(W0f, W0pf);
  pack_w0_mfma<<<32, 256, 0, stream>>>(W0b, W0pb);
  pack_w1_mfma<<<256, 256, 0, stream>>>(W1f, W1pf);
  pack_w1_mfma<<<256, 256, 0, stream>>>(W1b, W1pb);
  pack_x_f16<<<2048, 256, 0, stream>>>(x, xi);
  permute_cols<<<4, 256, 0, stream>>>(b0f, bp0f, 1);
  permute_cols<<<4, 256, 0, stream>>>(b0b, bp0b, 1);
  permute_cols<<<4, 256, 0, stream>>>(b1f, bp1f, 1);
  permute_cols<<<4, 256, 0, stream>>>(b1b, bp1b, 1);

  // ---- layer 0: fused proj+scan, single launch; tags 1..1024 ----
  lstm_scan_mfma<1><<<32, 512, 0, stream>>>(
      nullptr, xi, W0pf, W0pb, bp0f, bp0b, Up00, Up01, carry_c,
      payl, flagw, 0, T_, 0, h0, nullptr, nullptr);

  // ---- layer 1: h0 -> out (fused dense head); tags 1025..2048 ----
  init_out<<<(out_size + 255) / 256, 256, 0, stream>>>(out, bd, out_size);
  const int nch = T_ / Tc;
  const dim3 pgrid(Tc / 16, B_, 2);
  for (int ci = 0; ci < nch; ++ci) {
    int s0c = ci * Tc;
    proj1_mfma<<<pgrid, 256, 0, stream>>>(h0, W1pf, W1pb, bp1f, bp1b,
                                          xpc, s0c, Tc);
    lstm_scan_mfma<0><<<32, 512, 0, stream>>>(
        xpc, nullptr, nullptr, nullptr, nullptr, nullptr, Up10, Up11, carry_c,
        payl, flagw, s0c, Tc, 1024, nullptr, Wd, out);
  }
}

// Round 19
// 5923.518 us; speedup vs baseline: 1.3279x; 1.0869x over previous
//
#include <hip/hip_runtime.h>
#include <hip/hip_bf16.h>
#include <cstdint>
#include <cstddef>

#define B_ 64
#define T_ 1024

typedef _Float16 half_t;
typedef __attribute__((ext_vector_type(8))) _Float16 half8;
typedef __attribute__((ext_vector_type(4))) float f32x4;
typedef __attribute__((ext_vector_type(8))) unsigned short ushort8;

__device__ __forceinline__ float sigm(float x) { return 1.f / (1.f + __expf(-x)); }
__device__ __forceinline__ float tanh_fast(float x) {
  float e = __expf(2.f * x);
  return 1.f - 2.f / (e + 1.f);
}

// Permute columns into gate-interleaved order: dst[k][hc*4+g] = src[k][g*256+hc]
__global__ __launch_bounds__(256) void permute_cols(const float* __restrict__ src,
                                                    float* __restrict__ dst, int K) {
  int idx = blockIdx.x * 256 + threadIdx.x;
  if (idx >= K * 1024) return;
  int n = idx & 1023;
  size_t k = (size_t)(idx >> 10);
  dst[idx] = src[(k << 10) + ((size_t)(n & 3) << 8) + (n >> 2)];
}

// U [256][1024] (gate-blocked) -> MFMA B-fragment order, f16:
// dst flat [wgc(8)][w(4)][n(2)][s(8)][lane(64)][8]
// value = U[k = s*32 + (lane>>4)*8 + j][col' = wgc*128 + w*32 + n*16 + (lane&15)]
__global__ __launch_bounds__(256) void pack_u_mfma(const float* __restrict__ src,
                                                   half_t* __restrict__ dst) {
  int tid = blockIdx.x * 256 + threadIdx.x;  // 32768 lines
  int l = tid & 63;
  int s = (tid >> 6) & 7;
  int n = (tid >> 9) & 1;
  int w = (tid >> 10) & 3;
  int wgc = (tid >> 12) & 7;
  int col = wgc * 128 + w * 32 + n * 16 + (l & 15);
  int hc = col >> 2, g = col & 3;
  int k0 = s * 32 + (l >> 4) * 8;
  half8 v;
#pragma unroll
  for (int j = 0; j < 8; ++j)
    v[j] = (half_t)src[(size_t)(k0 + j) * 1024 + (g << 8) + hc];
  *(half8*)(dst + (size_t)tid * 8) = v;
}

// W0 [64][1024] (gate-blocked) -> MFMA B-frags, f16:
// line = wgc*1024 + w*256 + n*128 + ks*64 + l ;
// value = W0[ks*32+(l>>4)*8+j][col' = wgc*128+w*32+n*16+(l&15)]
__global__ __launch_bounds__(256) void pack_w0_mfma(const float* __restrict__ src,
                                                    half_t* __restrict__ dst) {
  int line = blockIdx.x * 256 + threadIdx.x;  // 8192 lines
  int l = line & 63;
  int ks = (line >> 6) & 1;
  int n = (line >> 7) & 1;
  int w = (line >> 8) & 3;
  int wgc = (line >> 10) & 7;
  int col = wgc * 128 + w * 32 + n * 16 + (l & 15);
  int sc = ((col & 3) << 8) + (col >> 2);
  int k0 = ks * 32 + (l >> 4) * 8;
  half8 v;
#pragma unroll
  for (int j = 0; j < 8; ++j)
    v[j] = (half_t)src[(size_t)(k0 + j) * 1024 + sc];
  *(half8*)(dst + (size_t)line * 8) = v;
}

// W1 [512][1024] (gate-blocked) -> MFMA B-fragment order, f16:
// line idx = (nb*16 + ks)*64 + l ; value = W[ks*32+(l>>4)*8+j][col' = nb*16+(l&15)]
__global__ __launch_bounds__(256) void pack_w1_mfma(const float* __restrict__ src,
                                                    half_t* __restrict__ dst) {
  int tid = blockIdx.x * 256 + threadIdx.x;  // 65536 lines
  int l = tid & 63;
  int ks = (tid >> 6) & 15;
  int nb = tid >> 10;  // 0..63
  int colp = nb * 16 + (l & 15);
  int sc = ((colp & 3) << 8) + (colp >> 2);
  int k0 = ks * 32 + (l >> 4) * 8;
  half8 v;
#pragma unroll
  for (int j = 0; j < 8; ++j)
    v[j] = (half_t)src[(size_t)(k0 + j) * 1024 + sc];
  *(half8*)(dst + (size_t)tid * 8) = v;
}

// x [B][T][64] f32 -> f16 A-layout image xi[bg(4)][t][128 lines][8]:
// line (within bg,t) = ks*64 + q*16 + b ; value = x[bg*16+b][t][ks*32+q*8+j]
__global__ __launch_bounds__(256) void pack_x_f16(const float* __restrict__ x,
                                                  unsigned short* __restrict__ xi) {
  int idx = blockIdx.x * 256 + threadIdx.x;  // 524288 lines
  int b = idx & 15;
  int q = (idx >> 4) & 3;
  int ks = (idx >> 6) & 1;
  int t = (idx >> 7) & 1023;
  int bg = idx >> 17;
  const float* src = x + ((size_t)(bg * 16 + b) * T_ + t) * 64 + ks * 32 + q * 8;
  ushort8 v;
#pragma unroll
  for (int j = 0; j < 8; ++j) {
    half_t h = (half_t)src[j];
    v[j] = __builtin_bit_cast(unsigned short, h);
  }
  *(ushort8*)(xi + (size_t)idx * 8) = v;
}

__global__ __launch_bounds__(256) void init_out(float* __restrict__ out,
                                                const float* __restrict__ bd, int n) {
  int i = blockIdx.x * 256 + threadIdx.x;
  if (i < n) out[i] = bd[0];
}

__global__ __launch_bounds__(256) void diag_out(float* __restrict__ out, int n, float v) {
  int i = blockIdx.x * 256 + threadIdx.x;
  if (i < n) out[i] = (i == 0) ? v : 0.f;
}

// Layer-1 projection (f16 MFMA; K=512), streaming traffic non-temporal.
// Standalone kernel: used only for chunk 0 (later chunks ride co-launched
// inside the scan kernel's extra blocks).
__global__ __launch_bounds__(256) void proj1_mfma(
    const unsigned short* __restrict__ h0,
    const half_t* __restrict__ Wf, const half_t* __restrict__ Wb,
    const float* __restrict__ bpf, const float* __restrict__ bpb,
    float* __restrict__ xp, int s0, int Tc) {
  const int dir = blockIdx.z;
  const half_t* Wpk = dir ? Wb : Wf;
  const float* bs = dir ? bpb : bpf;
  const int b = blockIdx.y;
  const int mt = blockIdx.x;
  const int tid = threadIdx.x;
  const int l = tid & 63, w = tid >> 6;

  __shared__ __align__(16) unsigned short A_lds[16][520];  // +8 pad

  {
    int r = tid >> 4, c16 = tid & 15;
    int sl = mt * 16 + r;
    int t = dir ? (T_ - 1 - s0 - sl) : (s0 + sl);
    const ushort8* srcp =
        (const ushort8*)(h0 + ((size_t)b * T_ + t) * 512 + c16 * 32);
#pragma unroll
    for (int u = 0; u < 4; ++u)
      *(ushort8*)&A_lds[r][c16 * 32 + u * 8] = __builtin_nontemporal_load(srcp + u);
  }
  __syncthreads();

  f32x4 acc[16];
#pragma unroll
  for (int n = 0; n < 16; ++n) acc[n] = (f32x4){0.f, 0.f, 0.f, 0.f};

  for (int ks = 0; ks < 16; ++ks) {
    half8 a = *(const half8*)&A_lds[l & 15][ks * 32 + (l >> 4) * 8];
    const half_t* bp_ = Wpk + (((size_t)(w * 16) * 16 + ks) * 64 + l) * 8;
#pragma unroll
    for (int n = 0; n < 16; ++n) {
      half8 bfr = *(const half8*)(bp_ + (size_t)n * 16 * 64 * 8);
      acc[n] = __builtin_amdgcn_mfma_f32_16x16x32_f16(a, bfr, acc[n], 0, 0, 0);
    }
  }

#pragma unroll
  for (int n = 0; n < 16; ++n) {
    int col = (w * 16 + n) * 16 + (l & 15);
    float bias = bs[col];
#pragma unroll
    for (int r = 0; r < 4; ++r) {
      int sl = mt * 16 + (l >> 4) * 4 + r;
      __builtin_nontemporal_store(
          acc[n][r] + bias,
          &xp[(((size_t)dir * B_ + b) * Tc + sl) * 1024 + col]);
    }
  }
}

// MFMA scan (round-18 structure) + optional co-launched projection blocks.
// Blocks 0..31: scan. unit = blk & 7 (XCD-local), wgc = blk >> 3 in [0,4);
// 512 threads = 8 waves = 2 merged producer slots. Protocol: payload publish
// -> vmcnt(0) drain -> tagged flag -> throttled poll (tid<4) -> bulk load.
// Blocks >= 32 (L0=0 launches only): proj1 for chunk s0p into xpn (tid<256
// active) — fully independent of the scan (reads h0, writes the ping-pong
// buffer), runs on the ~220 CUs the scan leaves idle.
template <int L0>
__global__ __launch_bounds__(512, 1) void lstm_scan_mfma(
    const float* __restrict__ xp,
    const unsigned short* __restrict__ xi,
    const half_t* __restrict__ W0f_, const half_t* __restrict__ W0b_,
    const float* __restrict__ b0f_, const float* __restrict__ b0b_,
    const half_t* __restrict__ Upk_f, const half_t* __restrict__ Upk_b,
    float* __restrict__ carry_c,
    unsigned* __restrict__ payl, unsigned* __restrict__ flagw,
    int s0, int Tc, int tagbase,
    unsigned short* __restrict__ hout,   // f16 row-major [B][T][512]
    const float* __restrict__ Wd, float* __restrict__ out,
    // co-launched proj (L0=0, blocks >= 32):
    const unsigned short* __restrict__ h0src,
    const half_t* __restrict__ W1f_, const half_t* __restrict__ W1b_,
    const float* __restrict__ bp1f_, const float* __restrict__ bp1b_,
    float* __restrict__ xpn, int s0p) {
  // unified LDS carve (scan: 10.75 KB; proj: 16.25 KB)
  __shared__ __align__(16) unsigned short shmem[16 * 520];
  const int tid = threadIdx.x;

  if (!L0 && blockIdx.x >= 32) {
    // ---------------- projection block ----------------
    unsigned short(*A2)[520] = (unsigned short(*)[520])shmem;
    int pb = blockIdx.x - 32;
    int mpt = Tc / 16;
    int mt = pb % mpt;
    int b = (pb / mpt) % B_;
    int dir = pb / (mpt * B_);
    const half_t* Wpk = dir ? W1b_ : W1f_;
    const float* bs = dir ? bp1b_ : bp1f_;
    const int l = tid & 63, w = tid >> 6;

    if (tid < 256) {
      int r = tid >> 4, c16 = tid & 15;
      int sl = mt * 16 + r;
      int t = dir ? (T_ - 1 - s0p - sl) : (s0p + sl);
      const ushort8* srcp =
          (const ushort8*)(h0src + ((size_t)b * T_ + t) * 512 + c16 * 32);
#pragma unroll
      for (int u = 0; u < 4; ++u)
        *(ushort8*)&A2[r][c16 * 32 + u * 8] = __builtin_nontemporal_load(srcp + u);
    }
    __syncthreads();
    if (tid < 256) {
      f32x4 acc[16];
#pragma unroll
      for (int n = 0; n < 16; ++n) acc[n] = (f32x4){0.f, 0.f, 0.f, 0.f};
      for (int ks = 0; ks < 16; ++ks) {
        half8 a = *(const half8*)&A2[l & 15][ks * 32 + (l >> 4) * 8];
        const half_t* bp_ = Wpk + (((size_t)(w * 16) * 16 + ks) * 64 + l) * 8;
#pragma unroll
        for (int n = 0; n < 16; ++n) {
          half8 bfr = *(const half8*)(bp_ + (size_t)n * 16 * 64 * 8);
          acc[n] = __builtin_amdgcn_mfma_f32_16x16x32_f16(a, bfr, acc[n], 0, 0, 0);
        }
      }
#pragma unroll
      for (int n = 0; n < 16; ++n) {
        int col = (w * 16 + n) * 16 + (l & 15);
        float bias = bs[col];
#pragma unroll
        for (int r = 0; r < 4; ++r) {
          int sl = mt * 16 + (l >> 4) * 4 + r;
          __builtin_nontemporal_store(
              acc[n][r] + bias,
              &xpn[(((size_t)dir * B_ + b) * Tc + sl) * 1024 + col]);
        }
      }
    }
    return;
  }

  // ---------------- scan block (round-18 body) ----------------
  unsigned short* A_lds = shmem;            // 4096 u16
  unsigned short* hstage = shmem + 4096;    // 1024 u16
  float* red_sm = (float*)(shmem + 5120);   // 128 f32

  const int blk = blockIdx.x;
  const int unit = blk & 7;   // XCD-local: same-unit WGs share blk%8
  const int wgc = blk >> 3;   // 0..3
  const int dir = unit & 1;
  const int bg = unit >> 1;
  const int b0u = bg * 16;
  const int l = tid & 63;
  const int w8 = tid >> 6;       // 0..7
  const int wgco = wgc * 2 + (w8 >> 2);  // producer slot (0..7)
  const int w = w8 & 3;                  // wave-in-slot

  const half_t* Upk = dir ? Upk_b : Upk_f;
  half8 U[2][8];
  {
    const half_t* up = Upk + (size_t)(wgco * 4 + w) * 8192;
#pragma unroll
    for (int n = 0; n < 2; ++n)
#pragma unroll
      for (int s = 0; s < 8; ++s)
        U[n][s] = *(const half8*)(up + ((size_t)(n * 8 + s) * 64 + l) * 8);
  }

  const int b_lane = 4 * (l >> 4) + (l & 3);
  const int hcb = wgco * 32 + w * 8 + ((l >> 2) & 3);  // + n*4
  const int colb = wgco * 128 + w * 32 + (l & 15);     // + n*16
  float cst[2];
#pragma unroll
  for (int n = 0; n < 2; ++n)
    cst[n] = (s0 == 0) ? 0.f
        : carry_c[((size_t)dir * B_ + b0u + b_lane) * 256 + hcb + n * 4];

  float wdl[2] = {0.f, 0.f};
  half8 W0r[2][2];
  float bias0[2] = {0.f, 0.f};
  const unsigned short* xib = nullptr;
  if (L0) {
    const half_t* W0pk = dir ? W0b_ : W0f_;
    const float* bs0 = dir ? b0b_ : b0f_;
#pragma unroll
    for (int n = 0; n < 2; ++n) {
      bias0[n] = bs0[colb + n * 16];
#pragma unroll
      for (int ks = 0; ks < 2; ++ks)
        W0r[n][ks] = *(const half8*)(W0pk +
            ((size_t)(((wgco * 4 + w) * 2 + n) * 2 + ks) * 64 + l) * 8);
    }
    xib = xi + (size_t)bg * T_ * 1024;
  } else {
    wdl[0] = Wd[dir * 256 + hcb];
    wdl[1] = Wd[dir * 256 + hcb + 4];
  }

  unsigned* payl_u = payl + (size_t)unit * 4096;   // 2 slots x 2048 u32
  unsigned* flag_u = flagw + unit * 16;            // 2 slots x 8 (4 used)

  if (s0 == 0) {
#pragma unroll
    for (int i = 0; i < 4; ++i) ((unsigned*)A_lds)[tid * 4 + i] = 0u;
  } else {
    unsigned dd[4];
#pragma unroll
    for (int i = 0; i < 4; ++i)
      dd[i] = __hip_atomic_load(payl_u + 2048 + tid * 4 + i,
                                __ATOMIC_RELAXED, __HIP_MEMORY_SCOPE_AGENT);
#pragma unroll
    for (int i = 0; i < 4; ++i)
      ((unsigned*)A_lds)[tid * 4 + i] = dd[i];
  }
  __syncthreads();

  const float* xpu = L0 ? nullptr : (xp + (size_t)(dir * B_ + b0u) * Tc * 1024);

  float xpre[2][4];
  half8 xfre[2];
  {
    if (L0) {
      int t0f = dir ? (T_ - 1 - s0) : s0;
#pragma unroll
      for (int ks = 0; ks < 2; ++ks)
        xfre[ks] = __builtin_nontemporal_load(
            (const half8*)((const half_t*)xib + (size_t)t0f * 1024 +
                           ((ks * 4 + (l >> 4)) * 16 + (l & 15)) * 8));
    } else {
#pragma unroll
      for (int n = 0; n < 2; ++n)
#pragma unroll
        for (int r = 0; r < 4; ++r)
          xpre[n][r] = __builtin_nontemporal_load(
              &xpu[((size_t)(4 * (l >> 4) + r) * Tc) * 1024 + colb + n * 16]);
    }
  }

  // hstage u16 index: slice (w8>>2) then slice-local layout
  const int hbl = (w8 >> 2) * 512 + (w * 16 + b_lane) * 8 + ((l >> 2) & 3);

  for (int sl = 0; sl < Tc; ++sl) {
    const int s = s0 + sl;
    const int t = dir ? (T_ - 1 - s) : s;
    const int slot = s & 1;

    f32x4 acc[2];
    if (L0) {
#pragma unroll
      for (int n = 0; n < 2; ++n)
#pragma unroll
        for (int r = 0; r < 4; ++r) acc[n][r] = bias0[n];
      half8 xa0 = xfre[0], xa1 = xfre[1];
#pragma unroll
      for (int n = 0; n < 2; ++n) {
        acc[n] = __builtin_amdgcn_mfma_f32_16x16x32_f16(xa0, W0r[n][0], acc[n], 0, 0, 0);
        acc[n] = __builtin_amdgcn_mfma_f32_16x16x32_f16(xa1, W0r[n][1], acc[n], 0, 0, 0);
      }
    } else {
#pragma unroll
      for (int n = 0; n < 2; ++n)
#pragma unroll
        for (int r = 0; r < 4; ++r) acc[n][r] = xpre[n][r];
    }

    // A fragments: lane l = h[b = l&15][k = sK*32 + (l>>4)*8 + j]
    half8 a[8];
#pragma unroll
    for (int sK = 0; sK < 8; ++sK)
      a[sK] = *(const half8*)&((const half_t*)A_lds)[((sK * 4 + (l >> 4)) * 16 + (l & 15)) * 8];

#pragma unroll
    for (int sK = 0; sK < 8; ++sK) {
      acc[0] = __builtin_amdgcn_mfma_f32_16x16x32_f16(a[sK], U[0][sK], acc[0], 0, 0, 0);
      acc[1] = __builtin_amdgcn_mfma_f32_16x16x32_f16(a[sK], U[1][sK], acc[1], 0, 0, 0);
    }

    float vhead = 0.f;
    unsigned short hu2[2];
#pragma unroll
    for (int n = 0; n < 2; ++n) {
      // 4x4 transpose across lane group (g = l&3) and regs: u[r] = Z[r][g]
      float v0 = acc[n][0], v1 = acc[n][1], v2 = acc[n][2], v3 = acc[n][3];
      float x0 = __shfl_xor(v1, 1), x1 = __shfl_xor(v0, 1);
      float x2 = __shfl_xor(v3, 1), x3 = __shfl_xor(v2, 1);
      float a0 = (l & 1) ? x0 : v0;
      float a1 = (l & 1) ? v1 : x1;
      float a2 = (l & 1) ? x2 : v2;
      float a3 = (l & 1) ? v3 : x3;
      float y0 = __shfl_xor(a2, 2), y1 = __shfl_xor(a3, 2);
      float y2 = __shfl_xor(a0, 2), y3 = __shfl_xor(a1, 2);
      float u0 = (l & 2) ? y0 : a0;
      float u1 = (l & 2) ? y1 : a1;
      float u2 = (l & 2) ? a2 : y2;
      float u3 = (l & 2) ? a3 : y3;

      float iG = sigm(u0), fG = sigm(u1), gG = tanh_fast(u2), oG = sigm(u3);
      float cn = fG * cst[n] + iG * gG;
      cst[n] = cn;
      float h = oG * tanh_fast(cn);

      if (!L0) vhead += h * wdl[n];
      hu2[n] = __builtin_bit_cast(unsigned short, (half_t)h);
      if (sl == Tc - 1)
        carry_c[((size_t)dir * B_ + b0u + b_lane) * 256 + hcb + n * 4] = cn;
    }
    hstage[hbl] = hu2[0];
    hstage[hbl + 4] = hu2[1];
    if (!L0) {
      vhead += __shfl_xor(vhead, 4);
      vhead += __shfl_xor(vhead, 8);
      if ((l & 12) == 0) red_sm[w8 * 16 + b_lane] = vhead;
    }
    __syncthreads();  // hstage + red_sm ready

    const unsigned* hs32 = (const unsigned*)hstage;  // u32[512]
    // coalesced payload publish: one u32 per thread = WG's 2KB (2 slices)
    __hip_atomic_store(payl_u + slot * 2048 + wgc * 512 + tid, hs32[tid],
                       __ATOMIC_RELAXED, __HIP_MEMORY_SCOPE_AGENT);

    // drain the payload store, then publish the flag
    asm volatile("s_waitcnt vmcnt(0)" ::: "memory");
    __syncthreads();
    const unsigned want = (unsigned)(tagbase + s + 1);
    if (tid == 0)
      __hip_atomic_store(flag_u + slot * 8 + wgc, want,
                         __ATOMIC_RELAXED, __HIP_MEMORY_SCOPE_AGENT);

    // h0 image write (NT) / fused head add: outside the drain window
    if (L0) {
      int sub = tid >> 8, r = tid & 255;
      int bb = r >> 4, cc = r & 15;
      __builtin_nontemporal_store(
          hs32[sub * 256 + (cc >> 2) * 64 + bb * 4 + (cc & 3)],
          (unsigned*)hout + ((size_t)(b0u + bb) * T_ + t) * 256 + dir * 128 +
              (wgc * 2 + sub) * 16 + cc);
    } else if (tid < 16) {
      float sum = ((red_sm[tid] + red_sm[16 + tid]) +
                   (red_sm[32 + tid] + red_sm[48 + tid])) +
                  ((red_sm[64 + tid] + red_sm[80 + tid]) +
                   (red_sm[96 + tid] + red_sm[112 + tid]));
      atomicAdd(out + (((size_t)(b0u + tid)) << 10) + t, sum);
    }

    if (sl + 1 < Tc) {
      // next-step input prefetch (NT): hides under the flag poll
      if (L0) {
        int tn = dir ? (T_ - 2 - s) : (s + 1);
#pragma unroll
        for (int ks = 0; ks < 2; ++ks)
          xfre[ks] = __builtin_nontemporal_load(
              (const half8*)((const half_t*)xib + (size_t)tn * 1024 +
                             ((ks * 4 + (l >> 4)) * 16 + (l & 15)) * 8));
      } else {
#pragma unroll
        for (int n = 0; n < 2; ++n)
#pragma unroll
          for (int r = 0; r < 4; ++r)
            xpre[n][r] = __builtin_nontemporal_load(
                &xpu[((size_t)(4 * (l >> 4) + r) * Tc + sl + 1) * 1024 + colb + n * 16]);
      }

      // throttled poll: 4 pollers (own flag skipped), hot spin
      if (tid < 4 && tid != wgc) {
        while (__hip_atomic_load(flag_u + slot * 8 + tid, __ATOMIC_RELAXED,
                                 __HIP_MEMORY_SCOPE_AGENT) != want) {}
      }
      __syncthreads();
      // bulk load: 4 u32/thread; own WG's 2 slices come from LDS
      unsigned dd[4];
      const int g = tid >> 6;  // producer slot (0..7) of words tid*4..tid*4+3
      if ((g >> 1) == wgc) {
#pragma unroll
        for (int i = 0; i < 4; ++i)
          dd[i] = hs32[(g & 1) * 256 + (tid & 63) * 4 + i];
      } else {
#pragma unroll
        for (int i = 0; i < 4; ++i)
          dd[i] = __hip_atomic_load(payl_u + slot * 2048 + tid * 4 + i,
                                    __ATOMIC_RELAXED, __HIP_MEMORY_SCOPE_AGENT);
      }
#pragma unroll
      for (int i = 0; i < 4; ++i)
        ((unsigned*)A_lds)[tid * 4 + i] = dd[i];
      __syncthreads();
    }
  }
}

extern "C" void kernel_launch(void* const* d_in, const int* in_sizes, int n_in,
                              void* d_out, int out_size, void* d_ws, size_t ws_size,
                              hipStream_t stream) {
  const float* x   = (const float*)d_in[0];
  const float* W0f = (const float*)d_in[1];
  const float* U0f = (const float*)d_in[2];
  const float* b0f = (const float*)d_in[3];
  const float* W0b = (const float*)d_in[4];
  const float* U0b = (const float*)d_in[5];
  const float* b0b = (const float*)d_in[6];
  const float* W1f = (const float*)d_in[7];
  const float* U1f = (const float*)d_in[8];
  const float* b1f = (const float*)d_in[9];
  const float* W1b = (const float*)d_in[10];
  const float* U1b = (const float*)d_in[11];
  const float* b1b = (const float*)d_in[12];
  const float* Wd  = (const float*)d_in[13];
  const float* bd  = (const float*)d_in[14];
  float* out = (float*)d_out;
  char* ws = (char*)d_ws;

  const size_t H0_BYTES   = (size_t)B_ * T_ * 512 * 2;     // 64 MiB f16
  const size_t UPK_BYTES  = (size_t)262144 * 2;            // 512 KiB
  const size_t W0PK_BYTES = (size_t)8192 * 8 * 2;          // 128 KiB f16
  const size_t W1PK_BYTES = (size_t)512 * 1024 * 2;        // 1 MiB f16
  const size_t XI_BYTES   = (size_t)B_ * T_ * 64 * 2;      // 8 MiB f16
  const size_t BP_BYTES   = 1024 * 4;
  const size_t CC_BYTES   = (size_t)2 * B_ * 256 * 4;      // 128 KiB
  const size_t PL_BYTES   = (size_t)8 * 4096 * 4;          // 128 KiB payload
  const size_t FL_BYTES   = 1024;
  const size_t REPACK = 4 * UPK_BYTES + 2 * W0PK_BYTES + 2 * W1PK_BYTES +
                        XI_BYTES + 4 * BP_BYTES + CC_BYTES + PL_BYTES +
                        FL_BYTES + 1024;

  // need TWO xp buffers (ping-pong for the co-launched projection)
  int Tc = 0;
  for (int tc = 128; tc >= 64; tc >>= 1) {
    size_t xpb = (size_t)2 * B_ * tc * 1024 * 4;
    if (H0_BYTES + REPACK + 2 * xpb <= ws_size) { Tc = tc; break; }
  }
  if (!Tc) {
    float v = 1000.f + (float)(ws_size >> 20);
    diag_out<<<(out_size + 255) / 256, 256, 0, stream>>>(out, out_size, v);
    return;
  }
  const size_t XP_BYTES = (size_t)2 * B_ * Tc * 1024 * 4;

  size_t off = 0;
  unsigned short* h0 = (unsigned short*)(ws + off); off += H0_BYTES;
  half_t* Up00 = (half_t*)(ws + off); off += UPK_BYTES;
  half_t* Up01 = (half_t*)(ws + off); off += UPK_BYTES;
  half_t* Up10 = (half_t*)(ws + off); off += UPK_BYTES;
  half_t* Up11 = (half_t*)(ws + off); off += UPK_BYTES;
  half_t* W0pf = (half_t*)(ws + off); off += W0PK_BYTES;
  half_t* W0pb = (half_t*)(ws + off); off += W0PK_BYTES;
  half_t* W1pf = (half_t*)(ws + off); off += W1PK_BYTES;
  half_t* W1pb = (half_t*)(ws + off); off += W1PK_BYTES;
  unsigned short* xi = (unsigned short*)(ws + off); off += XI_BYTES;
  float* bp0f = (float*)(ws + off); off += BP_BYTES;
  float* bp0b = (float*)(ws + off); off += BP_BYTES;
  float* bp1f = (float*)(ws + off); off += BP_BYTES;
  float* bp1b = (float*)(ws + off); off += BP_BYTES;
  float* carry_c = (float*)(ws + off); off += CC_BYTES;
  unsigned* payl = (unsigned*)(ws + off); off += PL_BYTES;
  unsigned* flagw = (unsigned*)(ws + off); off += FL_BYTES;
  off = (off + 255) & ~(size_t)255;
  float* xpA = (float*)(ws + off); off += XP_BYTES;
  float* xpB = (float*)(ws + off);

  // --- repacking ---
  pack_u_mfma<<<128, 256, 0, stream>>>(U0f, Up00);
  pack_u_mfma<<<128, 256, 0, stream>>>(U0b, Up01);
  pack_u_mfma<<<128, 256, 0, stream>>>(U1f, Up10);
  pack_u_mfma<<<128, 256, 0, stream>>>(U1b, Up11);
  pack_w0_mfma<<<32, 256, 0, stream>>>(W0f, W0pf);
  pack_w0_mfma<<<32, 256, 0, stream>>>(W0b, W0pb);
  pack_w1_mfma<<<256, 256, 0, stream>>>(W1f, W1pf);
  pack_w1_mfma<<<256, 256, 0, stream>>>(W1b, W1pb);
  pack_x_f16<<<2048, 256, 0, stream>>>(x, xi);
  permute_cols<<<4, 256, 0, stream>>>(b0f, bp0f, 1);
  permute_cols<<<4, 256, 0, stream>>>(b0b, bp0b, 1);
  permute_cols<<<4, 256, 0, stream>>>(b1f, bp1f, 1);
  permute_cols<<<4, 256, 0, stream>>>(b1b, bp1b, 1);

  // ---- layer 0: fused proj+scan, single launch; tags 1..1024 ----
  lstm_scan_mfma<1><<<32, 512, 0, stream>>>(
      nullptr, xi, W0pf, W0pb, bp0f, bp0b, Up00, Up01, carry_c,
      payl, flagw, 0, T_, 0, h0, nullptr, nullptr,
      nullptr, nullptr, nullptr, nullptr, nullptr, nullptr, 0);

  // ---- layer 1: per chunk, scan(ci) co-launched with proj(ci+1) ----
  init_out<<<(out_size + 255) / 256, 256, 0, stream>>>(out, bd, out_size);
  const int nch = T_ / Tc;
  const int nproj = (Tc / 16) * B_ * 2;
  // chunk 0 projection standalone
  proj1_mfma<<<dim3(Tc / 16, B_, 2), 256, 0, stream>>>(
      h0, W1pf, W1pb, bp1f, bp1b, xpA, 0, Tc);
  for (int ci = 0; ci < nch; ++ci) {
    int s0c = ci * Tc;
    float* xcur = (ci & 1) ? xpB : xpA;
    float* xnext = (ci & 1) ? xpA : xpB;
    int extra = (ci + 1 < nch) ? nproj : 0;
    lstm_scan_mfma<0><<<32 + extra, 512, 0, stream>>>(
        xcur, nullptr, nullptr, nullptr, nullptr, nullptr, Up10, Up11, carry_c,
        payl, flagw, s0c, Tc, 1024, nullptr, Wd, out,
        h0, W1pf, W1pb, bp1f, bp1b, xnext, (ci + 1) * Tc);
  }
}